// Round 9
// baseline (486.928 us; speedup 1.0000x reference)
//
#include <hip/hip_runtime.h>

#define T_STEPS 500
#define BATCH   128
#define NINPUT  6
#define NH      500
#define THRV    1.0f
#define BETAV   0.5f
#define W2T_STRIDE 512
#define JC      256    // j-chunk width in cur2
#define KT      128    // W2 rows per LDS tile

typedef unsigned long long ull;

static __device__ __forceinline__ ull rfl64(ull v) {
  unsigned lo = __builtin_amdgcn_readfirstlane((unsigned)v);
  unsigned hi = __builtin_amdgcn_readfirstlane((unsigned)(v >> 32));
  return ((ull)hi << 32) | lo;
}

// ---------------------------------------------------------------------------
// Transpose W2 [500][500] -> W2T [500][512] (padded stride, pad zeroed).
// ---------------------------------------------------------------------------
__global__ void transpose_w2(const float* __restrict__ W2, float* __restrict__ W2T) {
  int idx = blockIdx.x * 256 + threadIdx.x;
  if (idx < NH * W2T_STRIDE) {
    int i = idx >> 9;
    int j = idx & 511;
    W2T[idx] = (j < NH) ? W2[j * NH + i] : 0.f;
  }
}

// ---------------------------------------------------------------------------
// s1_seg: layer-1 LIF for t in [t0, t0+tc). grid = 128 (b), 512 thr = 8 waves.
// x slice staged in LDS; 2-deep prefetch; ballot -> one mask word per step.
// ---------------------------------------------------------------------------
__global__ __launch_bounds__(512) void s1_seg_kernel(
    const float* __restrict__ x,      // [T][B][6]
    const float* __restrict__ W1,     // [500][6]
    const float* __restrict__ b1,     // [500]
    float* __restrict__ m1state,      // [B][512]
    ull* __restrict__ s1seg,          // [tc][B][8]
    int t0, int tc)
{
  __shared__ float xs[T_STEPS * NINPUT];
  const int b = blockIdx.x;
  const int wid = threadIdx.x >> 6, lane = threadIdx.x & 63;

  for (int idx = threadIdx.x; idx < tc * NINPUT; idx += 512) {
    int h = idx / NINPUT, k = idx - h * NINPUT;
    xs[idx] = x[(size_t)((t0 + h) * BATCH + b) * NINPUT + k];
  }

  const int n = (wid << 6) + lane;
  const bool nv = (n < NH);
  float w[6], b1v;
  #pragma unroll
  for (int k = 0; k < 6; ++k) w[k] = nv ? W1[n * NINPUT + k] : 0.f;
  b1v = nv ? b1[n] : 0.f;
  float m1 = (t0 == 0) ? 0.f : m1state[b * 512 + n];

  __syncthreads();

  #define LOADL(hh, xr) do {                                   \
    const float* p_ = xs + (hh) * NINPUT;                      \
    float2 a_ = *(const float2*)p_;                            \
    float2 c_ = *(const float2*)(p_ + 2);                      \
    float2 d_ = *(const float2*)(p_ + 4);                      \
    xr[0]=a_.x; xr[1]=a_.y; xr[2]=c_.x;                        \
    xr[3]=c_.y; xr[4]=d_.x; xr[5]=d_.y;                        \
  } while (0)

  float X0[6], X1[6], X2[6];
  LOADL(0, X0);
  if (tc > 1) LOADL(1, X1); else LOADL(0, X1);

  for (int h = 0; h < tc; ++h) {
    int hp = h + 2; if (hp > tc - 1) hp = tc - 1;
    LOADL(hp, X2);
    float cur = b1v + w[0]*X0[0] + w[1]*X0[1] + w[2]*X0[2]
                    + w[3]*X0[3] + w[4]*X0[4] + w[5]*X0[5];
    float rst = (m1 > THRV) ? THRV : 0.f;
    m1 = BETAV * m1 + cur - rst;
    ull bm = __ballot((m1 > THRV) && nv);
    if (lane == 0) s1seg[((size_t)h * BATCH + b) * 8 + wid] = bm;
    #pragma unroll
    for (int k = 0; k < 6; ++k) { X0[k] = X1[k]; X1[k] = X2[k]; }
  }
  #undef LOADL
  m1state[b * 512 + n] = m1;
}

// ---------------------------------------------------------------------------
// cur2_seg: cur2[h][b][j] = b2[j] + sum_{i active} W2[j][i].
// grid = (128 b, 2 jc), 1024 thr = 16 waves (4/SIMD), 1 block/CU (128 KB LDS).
// 4-wide peel + per-(r,kt) mask prefetch -> 16+ outstanding ds_read_b128/SIMD.
// Accumulation order: kt ascending, word A then B, rows ascending, left-assoc
// (bit-identical to the previous rounds' order).
// ---------------------------------------------------------------------------
#define PEEL4(mm, roff, A) do {                                               \
  ull m_ = (mm);                                                              \
  while (m_) {                                                                \
    int i0 = __builtin_ctzll(m_); m_ &= m_ - 1;                               \
    bool v1 = (m_ != 0); int i1 = v1 ? __builtin_ctzll(m_) : i0;              \
    if (v1) m_ &= m_ - 1;                                                     \
    bool v2 = (m_ != 0); int i2 = v2 ? __builtin_ctzll(m_) : i0;              \
    if (v2) m_ &= m_ - 1;                                                     \
    bool v3 = (m_ != 0); int i3 = v3 ? __builtin_ctzll(m_) : i0;              \
    if (v3) m_ &= m_ - 1;                                                     \
    float4 w0_ = W2L[(((roff) + i0) << 6) + lane];                            \
    float4 w1_ = W2L[(((roff) + i1) << 6) + lane];                            \
    float4 w2_ = W2L[(((roff) + i2) << 6) + lane];                            \
    float4 w3_ = W2L[(((roff) + i3) << 6) + lane];                            \
    A.x += w0_.x; A.y += w0_.y; A.z += w0_.z; A.w += w0_.w;                   \
    if (v1) { A.x += w1_.x; A.y += w1_.y; A.z += w1_.z; A.w += w1_.w; }       \
    if (v2) { A.x += w2_.x; A.y += w2_.y; A.z += w2_.z; A.w += w2_.w; }       \
    if (v3) { A.x += w3_.x; A.y += w3_.y; A.z += w3_.z; A.w += w3_.w; }       \
  }                                                                           \
} while (0)

__global__ __launch_bounds__(1024, 4) void cur2_seg_kernel(
    const ull* __restrict__ s1seg,    // [tc][B][8]
    const float* __restrict__ W2T,    // [500][512]
    const float* __restrict__ b2,     // [500]
    float* __restrict__ cur2seg,      // [tc][B][500]
    int tc)
{
  __shared__ float4 W2L[KT * (JC / 4)];   // 128 KB
  const int b = blockIdx.x, jc = blockIdx.y;
  const int tid = threadIdx.x;
  const int lane = tid & 63, wid = tid >> 6;   // wid 0..15
  const int j0 = jc * JC + (lane << 2);
  const bool jv = (j0 < NH);

  float4 b2v = make_float4(0.f, 0.f, 0.f, 0.f);
  if (jv) b2v = *(const float4*)(b2 + j0);

  for (int r = 0; r < 4; ++r) {
    float4 acc[8];
    #pragma unroll
    for (int g = 0; g < 8; ++g) acc[g] = make_float4(0.f, 0.f, 0.f, 0.f);

    for (int kt = 0; kt < 4; ++kt) {
      __syncthreads();
      for (int idx = tid; idx < KT * (JC / 4); idx += 1024) {
        int rr = idx >> 6, cc = idx & 63;
        int grow = kt * KT + rr;
        float4 v = make_float4(0.f, 0.f, 0.f, 0.f);
        if (grow < NH)
          v = *(const float4*)(W2T + (size_t)grow * W2T_STRIDE + jc * JC + (cc << 2));
        W2L[idx] = v;
      }
      __syncthreads();

      // prefetch this (r,kt)'s masks for all 8 h handled by this wave
      ull qA[8], qB[8];
      #pragma unroll
      for (int g = 0; g < 8; ++g) {
        int h = r * 128 + g * 16 + wid;
        if (h < tc) {
          const ull* mp = s1seg + ((size_t)h * BATCH + b) * 8 + 2 * kt;
          qA[g] = mp[0]; qB[g] = mp[1];
        } else { qA[g] = 0; qB[g] = 0; }
      }
      #pragma unroll
      for (int g = 0; g < 8; ++g) {
        ull mA = rfl64(qA[g]);
        ull mB = rfl64(qB[g]);
        PEEL4(mA, 0,  acc[g]);
        PEEL4(mB, 64, acc[g]);
      }
    }

    #pragma unroll
    for (int g = 0; g < 8; ++g) {
      int h = r * 128 + g * 16 + wid;
      if (h < tc && jv) {
        float4 v = make_float4(acc[g].x + b2v.x, acc[g].y + b2v.y,
                               acc[g].z + b2v.z, acc[g].w + b2v.w);
        *(float4*)(cur2seg + ((size_t)h * BATCH + b) * NH + j0) = v;
      }
    }
  }
}

// ---------------------------------------------------------------------------
// scan2_seg (+fused cur3 partials): m2 recurrence parallel over (b, j).
// grid = (128 b, 2 jh), 256 thr. Per 8-step chunk: serial m2 updates (VALU),
// then 16 independent 6-level shuffle reductions of spk*Wout (pipelined),
// lane0 writes float2 partial per wave per step -> cur3p[t][b][8].
// ---------------------------------------------------------------------------
__global__ __launch_bounds__(256) void scan2_seg_kernel(
    const float* __restrict__ cur2seg, // [tc][B][500]
    const float* __restrict__ Wout,    // [2][500]
    float* __restrict__ m2state,       // [B][512]
    float* __restrict__ cur3p,         // [T][B][8] float2
    int t0, int tc)
{
  const int b = blockIdx.x, jh = blockIdx.y;
  const int tid = threadIdx.x;
  const int lane = tid & 63, wid = tid >> 6;
  const int j = jh * 256 + tid;
  const bool jv = (j < NH);
  const int word = jh * 4 + wid;

  const float wo0 = jv ? Wout[j] : 0.f;
  const float wo1 = jv ? Wout[NH + j] : 0.f;
  float m2 = (t0 == 0) ? 0.f : m2state[b * 512 + j];

  #define LD2(h) ((jv && (h) < tc) ? cur2seg[((size_t)((h) < tc ? (h) : 0) * BATCH + b) * NH + j] : 0.f)
  float v[8], nv_[8];
  #pragma unroll
  for (int k = 0; k < 8; ++k) v[k] = LD2(k);

  for (int hc = 0; hc < tc; hc += 8) {
    #pragma unroll
    for (int k = 0; k < 8; ++k) nv_[k] = LD2(hc + 8 + k);

    float c0v[8], c1v[8];
    #pragma unroll
    for (int k = 0; k < 8; ++k) {
      int h = hc + k;
      if (h < tc) {
        float rst = (m2 > THRV) ? THRV : 0.f;
        m2 = BETAV * m2 + v[k] - rst;
        bool s = (m2 > THRV) && jv;
        c0v[k] = s ? wo0 : 0.f;
        c1v[k] = s ? wo1 : 0.f;
      } else { c0v[k] = 0.f; c1v[k] = 0.f; }
    }
    // 16 independent reduction chains per level -> latency pipelined
    #pragma unroll
    for (int off = 32; off; off >>= 1) {
      #pragma unroll
      for (int k = 0; k < 8; ++k) {
        c0v[k] += __shfl_xor(c0v[k], off);
        c1v[k] += __shfl_xor(c1v[k], off);
      }
    }
    if (lane == 0) {
      #pragma unroll
      for (int k = 0; k < 8; ++k) {
        int h = hc + k;
        if (h < tc)
          *(float2*)(cur3p + (((size_t)(t0 + h) * BATCH + b) * 8 + word) * 2) =
              make_float2(c0v[k], c1v[k]);
      }
    }
    #pragma unroll
    for (int k = 0; k < 8; ++k) v[k] = nv_[k];
  }
  #undef LD2
  m2state[b * 512 + j] = m2;
}

// ---------------------------------------------------------------------------
// scan3: combine 8 partials (fixed order) + bias, serial m3 scan,
// one thread per batch element, 4-step prefetch (float4 loads).
// ---------------------------------------------------------------------------
__global__ __launch_bounds__(128) void scan3_kernel(
    const float* __restrict__ cur3p,  // [T][B][8] float2
    const float* __restrict__ bout,   // [2]
    float* __restrict__ out)          // spk [T][B][2] then mem [T][B][2]
{
  const int b = threadIdx.x;
  const float bo0 = bout[0], bo1 = bout[1];
  float m0 = 0.f, m1v = 0.f;

  float4 cb[4][4], nb[4][4];
  #pragma unroll
  for (int k = 0; k < 4; ++k)
    #pragma unroll
    for (int q = 0; q < 4; ++q)
      cb[k][q] = *(const float4*)(cur3p + (((size_t)k * BATCH + b) * 8) * 2 + q * 4);

  for (int tcc = 0; tcc < T_STEPS; tcc += 4) {
    #pragma unroll
    for (int k = 0; k < 4; ++k) {
      int tn = tcc + 4 + k; if (tn > T_STEPS - 1) tn = T_STEPS - 1;
      #pragma unroll
      for (int q = 0; q < 4; ++q)
        nb[k][q] = *(const float4*)(cur3p + (((size_t)tn * BATCH + b) * 8) * 2 + q * 4);
    }
    #pragma unroll
    for (int k = 0; k < 4; ++k) {
      int t = tcc + k;
      if (t < T_STEPS) {
        float c0 = ((cb[k][0].x + cb[k][0].z) + (cb[k][1].x + cb[k][1].z))
                 + ((cb[k][2].x + cb[k][2].z) + (cb[k][3].x + cb[k][3].z)) + bo0;
        float c1 = ((cb[k][0].y + cb[k][0].w) + (cb[k][1].y + cb[k][1].w))
                 + ((cb[k][2].y + cb[k][2].w) + (cb[k][3].y + cb[k][3].w)) + bo1;
        float r0 = (m0  > THRV) ? THRV : 0.f;
        float r1 = (m1v > THRV) ? THRV : 0.f;
        m0  = BETAV * m0  + c0 - r0;
        m1v = BETAV * m1v + c1 - r1;
        size_t o = (size_t)(t * BATCH + b) * 2;
        out[o]     = (m0  > THRV) ? 1.f : 0.f;
        out[o + 1] = (m1v > THRV) ? 1.f : 0.f;
        out[(size_t)T_STEPS * BATCH * 2 + o]     = m0;
        out[(size_t)T_STEPS * BATCH * 2 + o + 1] = m1v;
      }
    }
    #pragma unroll
    for (int k = 0; k < 4; ++k)
      #pragma unroll
      for (int q = 0; q < 4; ++q) cb[k][q] = nb[k][q];
  }
}

extern "C" void kernel_launch(void* const* d_in, const int* in_sizes, int n_in,
                              void* d_out, int out_size, void* d_ws, size_t ws_size,
                              hipStream_t stream) {
  const float* x    = (const float*)d_in[0];
  const float* W1   = (const float*)d_in[1];
  const float* b1   = (const float*)d_in[2];
  const float* W2   = (const float*)d_in[3];
  const float* b2   = (const float*)d_in[4];
  const float* Wout = (const float*)d_in[5];
  const float* bout = (const float*)d_in[6];
  float* out = (float*)d_out;

  // ---- carve workspace (all 512-aligned) ----
  size_t off = 0;
  char* base = (char*)d_ws;
  auto carve = [&](size_t bytes) -> char* {
    char* r = base + off;
    off += (bytes + 511) & ~(size_t)511;
    return r;
  };
  float* W2T     = (float*)carve((size_t)NH * W2T_STRIDE * 4);
  float* m1state = (float*)carve((size_t)BATCH * 512 * 4);
  float* m2state = (float*)carve((size_t)BATCH * 512 * 4);
  float* cur3p   = (float*)carve((size_t)T_STEPS * BATCH * 8 * 2 * 4);  // 4.096 MB

  const size_t per_t = ((size_t)BATCH * 8 * 8)      // s1seg
                     + ((size_t)BATCH * NH * 4);    // cur2seg
  long long avail = (long long)ws_size - (long long)off - 4096;
  int TSEG = (avail > 0) ? (int)(avail / (long long)per_t) : 1;
  if (TSEG > T_STEPS) TSEG = T_STEPS;
  if (TSEG < 1) TSEG = 1;

  ull*   s1seg   = (ull*)carve((size_t)TSEG * BATCH * 8 * 8);
  float* cur2seg = (float*)carve((size_t)TSEG * BATCH * NH * 4);

  transpose_w2<<<(NH * W2T_STRIDE + 255) / 256, 256, 0, stream>>>(W2, W2T);

  for (int t0 = 0; t0 < T_STEPS; t0 += TSEG) {
    int tc = T_STEPS - t0; if (tc > TSEG) tc = TSEG;
    s1_seg_kernel<<<BATCH, 512, 0, stream>>>(x, W1, b1, m1state, s1seg, t0, tc);
    cur2_seg_kernel<<<dim3(BATCH, 2), 1024, 0, stream>>>(s1seg, W2T, b2, cur2seg, tc);
    scan2_seg_kernel<<<dim3(BATCH, 2), 256, 0, stream>>>(cur2seg, Wout, m2state, cur3p, t0, tc);
  }
  scan3_kernel<<<1, 128, 0, stream>>>(cur3p, bout, out);
}

// Round 10
// 390.875 us; speedup vs baseline: 1.2457x; 1.2457x over previous
//
#include <hip/hip_runtime.h>

#define T_STEPS 500
#define BATCH   128
#define NINPUT  6
#define NH      500
#define THRV    1.0f
#define BETAV   0.5f
#define W2T_STRIDE 512
#define NGC     8      // s2 mask words per (t,b)
#define JC      256    // j-chunk width in cur2
#define KT      128    // W2 rows per LDS tile

typedef unsigned long long ull;

static __device__ __forceinline__ ull rfl64(ull v) {
  unsigned lo = __builtin_amdgcn_readfirstlane((unsigned)v);
  unsigned hi = __builtin_amdgcn_readfirstlane((unsigned)(v >> 32));
  return ((ull)hi << 32) | lo;
}

// ---------------------------------------------------------------------------
// Transpose W2 [500][500] -> W2T [500][512] (padded stride, pad zeroed).
// ---------------------------------------------------------------------------
__global__ void transpose_w2(const float* __restrict__ W2, float* __restrict__ W2T) {
  int idx = blockIdx.x * 256 + threadIdx.x;
  if (idx < NH * W2T_STRIDE) {
    int i = idx >> 9;
    int j = idx & 511;
    W2T[idx] = (j < NH) ? W2[j * NH + i] : 0.f;
  }
}

// ---------------------------------------------------------------------------
// s1_seg: layer-1 LIF for t in [t0, t0+tc). grid = 128 (b), 512 thr = 8 waves.
// x slice staged in LDS; 2-deep prefetch; ballot -> one mask word per step.
// ---------------------------------------------------------------------------
__global__ __launch_bounds__(512) void s1_seg_kernel(
    const float* __restrict__ x,      // [T][B][6]
    const float* __restrict__ W1,     // [500][6]
    const float* __restrict__ b1,     // [500]
    float* __restrict__ m1state,      // [B][512]
    ull* __restrict__ s1seg,          // [tc][B][8]
    int t0, int tc)
{
  __shared__ float xs[T_STEPS * NINPUT];
  const int b = blockIdx.x;
  const int wid = threadIdx.x >> 6, lane = threadIdx.x & 63;

  for (int idx = threadIdx.x; idx < tc * NINPUT; idx += 512) {
    int h = idx / NINPUT, k = idx - h * NINPUT;
    xs[idx] = x[(size_t)((t0 + h) * BATCH + b) * NINPUT + k];
  }

  const int n = (wid << 6) + lane;
  const bool nv = (n < NH);
  float w[6], b1v;
  #pragma unroll
  for (int k = 0; k < 6; ++k) w[k] = nv ? W1[n * NINPUT + k] : 0.f;
  b1v = nv ? b1[n] : 0.f;
  float m1 = (t0 == 0) ? 0.f : m1state[b * 512 + n];

  __syncthreads();

  #define LOADL(hh, xr) do {                                   \
    const float* p_ = xs + (hh) * NINPUT;                      \
    float2 a_ = *(const float2*)p_;                            \
    float2 c_ = *(const float2*)(p_ + 2);                      \
    float2 d_ = *(const float2*)(p_ + 4);                      \
    xr[0]=a_.x; xr[1]=a_.y; xr[2]=c_.x;                        \
    xr[3]=c_.y; xr[4]=d_.x; xr[5]=d_.y;                        \
  } while (0)

  float X0[6], X1[6], X2[6];
  LOADL(0, X0);
  if (tc > 1) LOADL(1, X1); else LOADL(0, X1);

  for (int h = 0; h < tc; ++h) {
    int hp = h + 2; if (hp > tc - 1) hp = tc - 1;
    LOADL(hp, X2);
    float cur = b1v + w[0]*X0[0] + w[1]*X0[1] + w[2]*X0[2]
                    + w[3]*X0[3] + w[4]*X0[4] + w[5]*X0[5];
    float rst = (m1 > THRV) ? THRV : 0.f;
    m1 = BETAV * m1 + cur - rst;
    ull bm = __ballot((m1 > THRV) && nv);
    if (lane == 0) s1seg[((size_t)h * BATCH + b) * 8 + wid] = bm;
    #pragma unroll
    for (int k = 0; k < 6; ++k) { X0[k] = X1[k]; X1[k] = X2[k]; }
  }
  #undef LOADL
  m1state[b * 512 + n] = m1;
}

// ---------------------------------------------------------------------------
// cur2_seg: cur2[h][b][j] = b2[j] + sum_{i active} W2[j][i].
// grid = (128 b, 2 jc), 1024 thr = 16 waves (4/SIMD), 1 block/CU (128 KB LDS).
// 4-wide peel + per-(r,kt) mask prefetch -> deep ds_read_b128 pipelining.
// ---------------------------------------------------------------------------
#define PEEL4(mm, roff, A) do {                                               \
  ull m_ = (mm);                                                              \
  while (m_) {                                                                \
    int i0 = __builtin_ctzll(m_); m_ &= m_ - 1;                               \
    bool v1 = (m_ != 0); int i1 = v1 ? __builtin_ctzll(m_) : i0;              \
    if (v1) m_ &= m_ - 1;                                                     \
    bool v2 = (m_ != 0); int i2 = v2 ? __builtin_ctzll(m_) : i0;              \
    if (v2) m_ &= m_ - 1;                                                     \
    bool v3 = (m_ != 0); int i3 = v3 ? __builtin_ctzll(m_) : i0;              \
    if (v3) m_ &= m_ - 1;                                                     \
    float4 w0_ = W2L[(((roff) + i0) << 6) + lane];                            \
    float4 w1_ = W2L[(((roff) + i1) << 6) + lane];                            \
    float4 w2_ = W2L[(((roff) + i2) << 6) + lane];                            \
    float4 w3_ = W2L[(((roff) + i3) << 6) + lane];                            \
    A.x += w0_.x; A.y += w0_.y; A.z += w0_.z; A.w += w0_.w;                   \
    if (v1) { A.x += w1_.x; A.y += w1_.y; A.z += w1_.z; A.w += w1_.w; }       \
    if (v2) { A.x += w2_.x; A.y += w2_.y; A.z += w2_.z; A.w += w2_.w; }       \
    if (v3) { A.x += w3_.x; A.y += w3_.y; A.z += w3_.z; A.w += w3_.w; }       \
  }                                                                           \
} while (0)

__global__ __launch_bounds__(1024, 4) void cur2_seg_kernel(
    const ull* __restrict__ s1seg,    // [tc][B][8]
    const float* __restrict__ W2T,    // [500][512]
    const float* __restrict__ b2,     // [500]
    float* __restrict__ cur2seg,      // [tc][B][500]
    int tc)
{
  __shared__ float4 W2L[KT * (JC / 4)];   // 128 KB
  const int b = blockIdx.x, jc = blockIdx.y;
  const int tid = threadIdx.x;
  const int lane = tid & 63, wid = tid >> 6;   // wid 0..15
  const int j0 = jc * JC + (lane << 2);
  const bool jv = (j0 < NH);

  float4 b2v = make_float4(0.f, 0.f, 0.f, 0.f);
  if (jv) b2v = *(const float4*)(b2 + j0);

  for (int r = 0; r < 4; ++r) {
    float4 acc[8];
    #pragma unroll
    for (int g = 0; g < 8; ++g) acc[g] = make_float4(0.f, 0.f, 0.f, 0.f);

    for (int kt = 0; kt < 4; ++kt) {
      __syncthreads();
      for (int idx = tid; idx < KT * (JC / 4); idx += 1024) {
        int rr = idx >> 6, cc = idx & 63;
        int grow = kt * KT + rr;
        float4 v = make_float4(0.f, 0.f, 0.f, 0.f);
        if (grow < NH)
          v = *(const float4*)(W2T + (size_t)grow * W2T_STRIDE + jc * JC + (cc << 2));
        W2L[idx] = v;
      }
      __syncthreads();

      ull qA[8], qB[8];
      #pragma unroll
      for (int g = 0; g < 8; ++g) {
        int h = r * 128 + g * 16 + wid;
        if (h < tc) {
          const ull* mp = s1seg + ((size_t)h * BATCH + b) * 8 + 2 * kt;
          qA[g] = mp[0]; qB[g] = mp[1];
        } else { qA[g] = 0; qB[g] = 0; }
      }
      #pragma unroll
      for (int g = 0; g < 8; ++g) {
        ull mA = rfl64(qA[g]);
        ull mB = rfl64(qB[g]);
        PEEL4(mA, 0,  acc[g]);
        PEEL4(mB, 64, acc[g]);
      }
    }

    #pragma unroll
    for (int g = 0; g < 8; ++g) {
      int h = r * 128 + g * 16 + wid;
      if (h < tc && jv) {
        float4 v = make_float4(acc[g].x + b2v.x, acc[g].y + b2v.y,
                               acc[g].z + b2v.z, acc[g].w + b2v.w);
        *(float4*)(cur2seg + ((size_t)h * BATCH + b) * NH + j0) = v;
      }
    }
  }
}

// ---------------------------------------------------------------------------
// scan2_seg: m2 recurrence, parallel over (b, j). grid = (128 b, 2 jh),
// 256 thr. Thread j scans its chain; 8-deep static prefetch; ballot -> s2seg.
// ---------------------------------------------------------------------------
__global__ __launch_bounds__(256) void scan2_seg_kernel(
    const float* __restrict__ cur2seg, // [tc][B][500]
    float* __restrict__ m2state,       // [B][512]
    ull* __restrict__ s2seg,           // [tc][B][8]
    int t0, int tc)
{
  const int b = blockIdx.x, jh = blockIdx.y;
  const int tid = threadIdx.x;
  const int lane = tid & 63, wid = tid >> 6;
  const int j = jh * 256 + tid;
  const bool jv = (j < NH);
  const int word = jh * 4 + wid;

  float m2 = (t0 == 0) ? 0.f : m2state[b * 512 + j];

  #define LD2(h) ((jv && (h) < tc) ? cur2seg[((size_t)((h) < tc ? (h) : 0) * BATCH + b) * NH + j] : 0.f)
  float v[8], nv_[8];
  #pragma unroll
  for (int k = 0; k < 8; ++k) v[k] = LD2(k);

  for (int hc = 0; hc < tc; hc += 8) {
    #pragma unroll
    for (int k = 0; k < 8; ++k) nv_[k] = LD2(hc + 8 + k);
    #pragma unroll
    for (int k = 0; k < 8; ++k) {
      int h = hc + k;
      if (h < tc) {
        float rst = (m2 > THRV) ? THRV : 0.f;
        m2 = BETAV * m2 + v[k] - rst;
        ull bm = __ballot((m2 > THRV) && jv);
        if (lane == 0) s2seg[((size_t)h * BATCH + b) * 8 + word] = bm;
      }
    }
    #pragma unroll
    for (int k = 0; k < 8; ++k) v[k] = nv_[k];
  }
  #undef LD2
  m2state[b * 512 + j] = m2;
}

// ---------------------------------------------------------------------------
// cur3_seg: cur3T[b][t] = Wout . s2[t][b] -- parallel over seg pairs.
// Transposed output layout so scan3's per-b reads are contiguous.
// ---------------------------------------------------------------------------
__global__ __launch_bounds__(256) void cur3_seg_kernel(
    const ull* __restrict__ s2seg,    // [tc][B][8]
    const float* __restrict__ Wout,   // [2][500]
    float* __restrict__ cur3T,        // [B][512] float2
    int t0, int tc)
{
  const int wid  = threadIdx.x >> 6;
  const int lane = threadIdx.x & 63;
  const int pl = blockIdx.x * 4 + wid;
  if (pl >= tc * BATCH) return;
  const int h  = pl >> 7;        // pl / BATCH
  const int bb = pl & 127;       // pl % BATCH

  float wa[NGC], wb[NGC];
  #pragma unroll
  for (int g = 0; g < NGC; ++g) {
    int j = g * 64 + lane;
    wa[g] = (j < NH) ? Wout[j] : 0.f;
    wb[g] = (j < NH) ? Wout[NH + j] : 0.f;
  }

  const ull* p = s2seg + (size_t)pl * 8;
  float c0 = 0.f, c1 = 0.f;
  #pragma unroll
  for (int g = 0; g < NGC; ++g) {
    ull mg = p[g];
    if ((mg >> lane) & 1ull) { c0 += wa[g]; c1 += wb[g]; }
  }
  #pragma unroll
  for (int off = 32; off; off >>= 1) {
    c0 += __shfl_xor(c0, off);
    c1 += __shfl_xor(c1, off);
  }
  if (lane == 0)
    *(float2*)(cur3T + ((size_t)bb * 512 + (t0 + h)) * 2) = make_float2(c0, c1);
}

// ---------------------------------------------------------------------------
// scan3: m3 recurrence, one block per batch element (distributed reads),
// 64 lanes. Lanes cooperatively load a 64-step chunk (next-chunk prefetched),
// then the wave walks the steps serially via __shfl broadcast; all lanes
// redundantly carry (m0,m1); lane k stores step k's outputs.
// ---------------------------------------------------------------------------
__global__ __launch_bounds__(64) void scan3_kernel(
    const float* __restrict__ cur3T,  // [B][512] float2
    const float* __restrict__ bout,   // [2]
    float* __restrict__ out)          // spk [T][B][2] then mem [T][B][2]
{
  const int b = blockIdx.x;
  const int lane = threadIdx.x;
  const float bo0 = bout[0], bo1 = bout[1];
  float m0 = 0.f, m1v = 0.f;

  float2 cur = *(const float2*)(cur3T + ((size_t)b * 512 + lane) * 2);

  for (int tcc = 0; tcc < T_STEPS; tcc += 64) {
    int tn = tcc + 64 + lane; if (tn > T_STEPS - 1) tn = T_STEPS - 1;
    float2 nxt = *(const float2*)(cur3T + ((size_t)b * 512 + tn) * 2);

    float c0 = cur.x + bo0, c1 = cur.y + bo1;
    int nsteps = T_STEPS - tcc; if (nsteps > 64) nsteps = 64;
    for (int k = 0; k < nsteps; ++k) {
      float cc0 = __shfl(c0, k);
      float cc1 = __shfl(c1, k);
      float r0 = (m0  > THRV) ? THRV : 0.f;
      float r1 = (m1v > THRV) ? THRV : 0.f;
      m0  = BETAV * m0  + cc0 - r0;
      m1v = BETAV * m1v + cc1 - r1;
      if (lane == k) {
        int t = tcc + k;
        size_t o = (size_t)(t * BATCH + b) * 2;
        out[o]     = (m0  > THRV) ? 1.f : 0.f;
        out[o + 1] = (m1v > THRV) ? 1.f : 0.f;
        out[(size_t)T_STEPS * BATCH * 2 + o]     = m0;
        out[(size_t)T_STEPS * BATCH * 2 + o + 1] = m1v;
      }
    }
    cur = nxt;
  }
}

extern "C" void kernel_launch(void* const* d_in, const int* in_sizes, int n_in,
                              void* d_out, int out_size, void* d_ws, size_t ws_size,
                              hipStream_t stream) {
  const float* x    = (const float*)d_in[0];
  const float* W1   = (const float*)d_in[1];
  const float* b1   = (const float*)d_in[2];
  const float* W2   = (const float*)d_in[3];
  const float* b2   = (const float*)d_in[4];
  const float* Wout = (const float*)d_in[5];
  const float* bout = (const float*)d_in[6];
  float* out = (float*)d_out;

  // ---- carve workspace (all 512-aligned) ----
  size_t off = 0;
  char* base = (char*)d_ws;
  auto carve = [&](size_t bytes) -> char* {
    char* r = base + off;
    off += (bytes + 511) & ~(size_t)511;
    return r;
  };
  float* W2T     = (float*)carve((size_t)NH * W2T_STRIDE * 4);
  float* m1state = (float*)carve((size_t)BATCH * 512 * 4);
  float* m2state = (float*)carve((size_t)BATCH * 512 * 4);
  float* cur3T   = (float*)carve((size_t)BATCH * 512 * 2 * 4);   // 512 KB

  const size_t per_t = ((size_t)BATCH * 8 * 8)      // s1seg
                     + ((size_t)BATCH * 8 * 8)      // s2seg
                     + ((size_t)BATCH * NH * 4);    // cur2seg
  long long avail = (long long)ws_size - (long long)off - 4096;
  int TSEG = (avail > 0) ? (int)(avail / (long long)per_t) : 1;
  if (TSEG > T_STEPS) TSEG = T_STEPS;
  if (TSEG < 1) TSEG = 1;

  ull*   s1seg   = (ull*)carve((size_t)TSEG * BATCH * 8 * 8);
  ull*   s2seg   = (ull*)carve((size_t)TSEG * BATCH * 8 * 8);
  float* cur2seg = (float*)carve((size_t)TSEG * BATCH * NH * 4);

  transpose_w2<<<(NH * W2T_STRIDE + 255) / 256, 256, 0, stream>>>(W2, W2T);

  for (int t0 = 0; t0 < T_STEPS; t0 += TSEG) {
    int tc = T_STEPS - t0; if (tc > TSEG) tc = TSEG;
    s1_seg_kernel<<<BATCH, 512, 0, stream>>>(x, W1, b1, m1state, s1seg, t0, tc);
    cur2_seg_kernel<<<dim3(BATCH, 2), 1024, 0, stream>>>(s1seg, W2T, b2, cur2seg, tc);
    scan2_seg_kernel<<<dim3(BATCH, 2), 256, 0, stream>>>(cur2seg, m2state, s2seg, t0, tc);
    cur3_seg_kernel<<<(tc * BATCH + 3) / 4, 256, 0, stream>>>(s2seg, Wout, cur3T, t0, tc);
  }
  scan3_kernel<<<BATCH, 64, 0, stream>>>(cur3T, bout, out);
}

// Round 11
// 373.256 us; speedup vs baseline: 1.3045x; 1.0472x over previous
//
#include <hip/hip_runtime.h>

#define T_STEPS 500
#define BATCH   128
#define NINPUT  6
#define NH      500
#define THRV    1.0f
#define BETAV   0.5f
#define W2T_STRIDE 512
#define CSTRIDE 512    // cur2seg row stride (padded)
#define NGC     8      // s2 mask words per (t,b)
#define JC      256    // j-chunk width in cur2
#define KT      128    // W2 rows per LDS tile

typedef unsigned long long ull;

static __device__ __forceinline__ ull rfl64(ull v) {
  unsigned lo = __builtin_amdgcn_readfirstlane((unsigned)v);
  unsigned hi = __builtin_amdgcn_readfirstlane((unsigned)(v >> 32));
  return ((ull)hi << 32) | lo;
}

// ---------------------------------------------------------------------------
// Transpose W2 [500][500] -> W2T [500][512] (padded stride, pad zeroed).
// ---------------------------------------------------------------------------
__global__ void transpose_w2(const float* __restrict__ W2, float* __restrict__ W2T) {
  int idx = blockIdx.x * 256 + threadIdx.x;
  if (idx < NH * W2T_STRIDE) {
    int i = idx >> 9;
    int j = idx & 511;
    W2T[idx] = (j < NH) ? W2[j * NH + i] : 0.f;
  }
}

// ---------------------------------------------------------------------------
// s1_seg: layer-1 LIF for t in [t0, t0+tc). grid = (128 b, 2 half), 256 thr.
// x slice staged in LDS; 2-deep prefetch; ballot -> one mask word per step.
// half h owns neurons [256h, 256h+256); wave w word = half*4+w.
// ---------------------------------------------------------------------------
__global__ __launch_bounds__(256) void s1_seg_kernel(
    const float* __restrict__ x,      // [T][B][6]
    const float* __restrict__ W1,     // [500][6]
    const float* __restrict__ b1,     // [500]
    float* __restrict__ m1state,      // [B][512]
    ull* __restrict__ s1seg,          // [tc][B][8]
    int t0, int tc)
{
  __shared__ float xs[T_STEPS * NINPUT];
  const int b = blockIdx.x, half = blockIdx.y;
  const int wid = threadIdx.x >> 6, lane = threadIdx.x & 63;

  for (int idx = threadIdx.x; idx < tc * NINPUT; idx += 256) {
    int h = idx / NINPUT, k = idx - h * NINPUT;
    xs[idx] = x[(size_t)((t0 + h) * BATCH + b) * NINPUT + k];
  }

  const int n = half * 256 + (wid << 6) + lane;
  const bool nv = (n < NH);
  const int word = half * 4 + wid;
  float w[6], b1v;
  #pragma unroll
  for (int k = 0; k < 6; ++k) w[k] = nv ? W1[n * NINPUT + k] : 0.f;
  b1v = nv ? b1[n] : 0.f;
  float m1 = (t0 == 0) ? 0.f : m1state[b * 512 + n];

  __syncthreads();

  #define LOADL(hh, xr) do {                                   \
    const float* p_ = xs + (hh) * NINPUT;                      \
    float2 a_ = *(const float2*)p_;                            \
    float2 c_ = *(const float2*)(p_ + 2);                      \
    float2 d_ = *(const float2*)(p_ + 4);                      \
    xr[0]=a_.x; xr[1]=a_.y; xr[2]=c_.x;                        \
    xr[3]=c_.y; xr[4]=d_.x; xr[5]=d_.y;                        \
  } while (0)

  float X0[6], X1[6], X2[6];
  LOADL(0, X0);
  if (tc > 1) LOADL(1, X1); else LOADL(0, X1);

  for (int h = 0; h < tc; ++h) {
    int hp = h + 2; if (hp > tc - 1) hp = tc - 1;
    LOADL(hp, X2);
    float cur = b1v + w[0]*X0[0] + w[1]*X0[1] + w[2]*X0[2]
                    + w[3]*X0[3] + w[4]*X0[4] + w[5]*X0[5];
    float rst = (m1 > THRV) ? THRV : 0.f;
    m1 = BETAV * m1 + cur - rst;
    ull bm = __ballot((m1 > THRV) && nv);
    if (lane == 0) s1seg[((size_t)h * BATCH + b) * 8 + word] = bm;
    #pragma unroll
    for (int k = 0; k < 6; ++k) { X0[k] = X1[k]; X1[k] = X2[k]; }
  }
  #undef LOADL
  m1state[b * 512 + n] = m1;
}

// ---------------------------------------------------------------------------
// cur2_seg: cur2[h][b][j] = b2[j] + sum_{i active} W2[j][i].
// grid = (128 b, 2 jc), 1024 thr = 16 waves (4/SIMD), 1 block/CU (128 KB LDS).
// 4-wide peel + per-(r,kt) mask prefetch -> deep ds_read_b128 pipelining.
// Output stride padded to 512 (pad lanes write zeros).
// ---------------------------------------------------------------------------
#define PEEL4(mm, roff, A) do {                                               \
  ull m_ = (mm);                                                              \
  while (m_) {                                                                \
    int i0 = __builtin_ctzll(m_); m_ &= m_ - 1;                               \
    bool v1 = (m_ != 0); int i1 = v1 ? __builtin_ctzll(m_) : i0;              \
    if (v1) m_ &= m_ - 1;                                                     \
    bool v2 = (m_ != 0); int i2 = v2 ? __builtin_ctzll(m_) : i0;              \
    if (v2) m_ &= m_ - 1;                                                     \
    bool v3 = (m_ != 0); int i3 = v3 ? __builtin_ctzll(m_) : i0;              \
    if (v3) m_ &= m_ - 1;                                                     \
    float4 w0_ = W2L[(((roff) + i0) << 6) + lane];                            \
    float4 w1_ = W2L[(((roff) + i1) << 6) + lane];                            \
    float4 w2_ = W2L[(((roff) + i2) << 6) + lane];                            \
    float4 w3_ = W2L[(((roff) + i3) << 6) + lane];                            \
    A.x += w0_.x; A.y += w0_.y; A.z += w0_.z; A.w += w0_.w;                   \
    if (v1) { A.x += w1_.x; A.y += w1_.y; A.z += w1_.z; A.w += w1_.w; }       \
    if (v2) { A.x += w2_.x; A.y += w2_.y; A.z += w2_.z; A.w += w2_.w; }       \
    if (v3) { A.x += w3_.x; A.y += w3_.y; A.z += w3_.z; A.w += w3_.w; }       \
  }                                                                           \
} while (0)

__global__ __launch_bounds__(1024, 4) void cur2_seg_kernel(
    const ull* __restrict__ s1seg,    // [tc][B][8]
    const float* __restrict__ W2T,    // [500][512]
    const float* __restrict__ b2,     // [500]
    float* __restrict__ cur2seg,      // [tc][B][512]
    int tc)
{
  __shared__ float4 W2L[KT * (JC / 4)];   // 128 KB
  const int b = blockIdx.x, jc = blockIdx.y;
  const int tid = threadIdx.x;
  const int lane = tid & 63, wid = tid >> 6;   // wid 0..15
  const int j0 = jc * JC + (lane << 2);
  const bool jv = (j0 < NH);

  float4 b2v = make_float4(0.f, 0.f, 0.f, 0.f);
  if (jv) b2v = *(const float4*)(b2 + j0);

  for (int r = 0; r < 4; ++r) {
    float4 acc[8];
    #pragma unroll
    for (int g = 0; g < 8; ++g) acc[g] = make_float4(0.f, 0.f, 0.f, 0.f);

    for (int kt = 0; kt < 4; ++kt) {
      __syncthreads();
      for (int idx = tid; idx < KT * (JC / 4); idx += 1024) {
        int rr = idx >> 6, cc = idx & 63;
        int grow = kt * KT + rr;
        float4 v = make_float4(0.f, 0.f, 0.f, 0.f);
        if (grow < NH)
          v = *(const float4*)(W2T + (size_t)grow * W2T_STRIDE + jc * JC + (cc << 2));
        W2L[idx] = v;
      }
      __syncthreads();

      ull qA[8], qB[8];
      #pragma unroll
      for (int g = 0; g < 8; ++g) {
        int h = r * 128 + g * 16 + wid;
        if (h < tc) {
          const ull* mp = s1seg + ((size_t)h * BATCH + b) * 8 + 2 * kt;
          qA[g] = mp[0]; qB[g] = mp[1];
        } else { qA[g] = 0; qB[g] = 0; }
      }
      #pragma unroll
      for (int g = 0; g < 8; ++g) {
        ull mA = rfl64(qA[g]);
        ull mB = rfl64(qB[g]);
        PEEL4(mA, 0,  acc[g]);
        PEEL4(mB, 64, acc[g]);
      }
    }

    #pragma unroll
    for (int g = 0; g < 8; ++g) {
      int h = r * 128 + g * 16 + wid;
      if (h < tc) {
        float4 v = make_float4(acc[g].x + b2v.x, acc[g].y + b2v.y,
                               acc[g].z + b2v.z, acc[g].w + b2v.w);
        *(float4*)(cur2seg + ((size_t)h * BATCH + b) * CSTRIDE + j0) = v;
      }
    }
  }
}

// ---------------------------------------------------------------------------
// scan2_seg: m2 recurrence. grid = (128 b, 4 jq) x 64 thr = 512 blocks.
// Lane owns j = jq*128+lane and j+64 (2 chains -> 2x ILP, 16 loads in
// flight per thread). Loads unconditional (padded stride 512, clamped h).
// Wave ballots are words jq*2 and jq*2+1 of s2seg[t][b][8].
// ---------------------------------------------------------------------------
__global__ __launch_bounds__(64) void scan2_seg_kernel(
    const float* __restrict__ cur2seg, // [tc][B][512]
    float* __restrict__ m2state,       // [B][512]
    ull* __restrict__ s2seg,           // [tc][B][8]
    int t0, int tc)
{
  const int b = blockIdx.x, jq = blockIdx.y;
  const int lane = threadIdx.x;
  const int ja = jq * 128 + lane;
  const int jb = ja + 64;
  const bool jva = (ja < NH), jvb = (jb < NH);
  const int wa = jq * 2, wb = wa + 1;

  float m2a = (t0 == 0) ? 0.f : m2state[b * 512 + ja];
  float m2b = (t0 == 0) ? 0.f : m2state[b * 512 + jb];

  #define LDA(h) cur2seg[((size_t)(((h) < tc) ? (h) : (tc - 1)) * BATCH + b) * CSTRIDE + ja]
  #define LDB(h) cur2seg[((size_t)(((h) < tc) ? (h) : (tc - 1)) * BATCH + b) * CSTRIDE + jb]
  float va[8], vb[8], na[8], nb[8];
  #pragma unroll
  for (int k = 0; k < 8; ++k) { va[k] = LDA(k); vb[k] = LDB(k); }

  for (int hc = 0; hc < tc; hc += 8) {
    #pragma unroll
    for (int k = 0; k < 8; ++k) { na[k] = LDA(hc + 8 + k); nb[k] = LDB(hc + 8 + k); }
    #pragma unroll
    for (int k = 0; k < 8; ++k) {
      int h = hc + k;
      if (h < tc) {
        float ra = (m2a > THRV) ? THRV : 0.f;
        float rb = (m2b > THRV) ? THRV : 0.f;
        m2a = BETAV * m2a + va[k] - ra;
        m2b = BETAV * m2b + vb[k] - rb;
        ull bma = __ballot((m2a > THRV) && jva);
        ull bmb = __ballot((m2b > THRV) && jvb);
        if (lane == 0) {
          ull* p = s2seg + ((size_t)h * BATCH + b) * 8;
          p[wa] = bma; p[wb] = bmb;
        }
      }
    }
    #pragma unroll
    for (int k = 0; k < 8; ++k) { va[k] = na[k]; vb[k] = nb[k]; }
  }
  #undef LDA
  #undef LDB
  m2state[b * 512 + ja] = m2a;
  m2state[b * 512 + jb] = m2b;
}

// ---------------------------------------------------------------------------
// cur3_seg: cur3T[b][t] = Wout . s2[t][b] -- parallel over seg pairs.
// Transposed output layout so scan3's per-b reads are contiguous.
// ---------------------------------------------------------------------------
__global__ __launch_bounds__(256) void cur3_seg_kernel(
    const ull* __restrict__ s2seg,    // [tc][B][8]
    const float* __restrict__ Wout,   // [2][500]
    float* __restrict__ cur3T,        // [B][512] float2
    int t0, int tc)
{
  const int wid  = threadIdx.x >> 6;
  const int lane = threadIdx.x & 63;
  const int pl = blockIdx.x * 4 + wid;
  if (pl >= tc * BATCH) return;
  const int h  = pl >> 7;        // pl / BATCH
  const int bb = pl & 127;       // pl % BATCH

  float wa[NGC], wb[NGC];
  #pragma unroll
  for (int g = 0; g < NGC; ++g) {
    int j = g * 64 + lane;
    wa[g] = (j < NH) ? Wout[j] : 0.f;
    wb[g] = (j < NH) ? Wout[NH + j] : 0.f;
  }

  const ull* p = s2seg + (size_t)pl * 8;
  float c0 = 0.f, c1 = 0.f;
  #pragma unroll
  for (int g = 0; g < NGC; ++g) {
    ull mg = p[g];
    if ((mg >> lane) & 1ull) { c0 += wa[g]; c1 += wb[g]; }
  }
  #pragma unroll
  for (int off = 32; off; off >>= 1) {
    c0 += __shfl_xor(c0, off);
    c1 += __shfl_xor(c1, off);
  }
  if (lane == 0)
    *(float2*)(cur3T + ((size_t)bb * 512 + (t0 + h)) * 2) = make_float2(c0, c1);
}

// ---------------------------------------------------------------------------
// scan3: m3 recurrence, one block per batch element, 64 lanes; chunk loads
// with prefetch, serial walk via __shfl broadcast; lane k stores step k.
// ---------------------------------------------------------------------------
__global__ __launch_bounds__(64) void scan3_kernel(
    const float* __restrict__ cur3T,  // [B][512] float2
    const float* __restrict__ bout,   // [2]
    float* __restrict__ out)          // spk [T][B][2] then mem [T][B][2]
{
  const int b = blockIdx.x;
  const int lane = threadIdx.x;
  const float bo0 = bout[0], bo1 = bout[1];
  float m0 = 0.f, m1v = 0.f;

  float2 cur = *(const float2*)(cur3T + ((size_t)b * 512 + lane) * 2);

  for (int tcc = 0; tcc < T_STEPS; tcc += 64) {
    int tn = tcc + 64 + lane; if (tn > T_STEPS - 1) tn = T_STEPS - 1;
    float2 nxt = *(const float2*)(cur3T + ((size_t)b * 512 + tn) * 2);

    float c0 = cur.x + bo0, c1 = cur.y + bo1;
    int nsteps = T_STEPS - tcc; if (nsteps > 64) nsteps = 64;
    for (int k = 0; k < nsteps; ++k) {
      float cc0 = __shfl(c0, k);
      float cc1 = __shfl(c1, k);
      float r0 = (m0  > THRV) ? THRV : 0.f;
      float r1 = (m1v > THRV) ? THRV : 0.f;
      m0  = BETAV * m0  + cc0 - r0;
      m1v = BETAV * m1v + cc1 - r1;
      if (lane == k) {
        int t = tcc + k;
        size_t o = (size_t)(t * BATCH + b) * 2;
        out[o]     = (m0  > THRV) ? 1.f : 0.f;
        out[o + 1] = (m1v > THRV) ? 1.f : 0.f;
        out[(size_t)T_STEPS * BATCH * 2 + o]     = m0;
        out[(size_t)T_STEPS * BATCH * 2 + o + 1] = m1v;
      }
    }
    cur = nxt;
  }
}

extern "C" void kernel_launch(void* const* d_in, const int* in_sizes, int n_in,
                              void* d_out, int out_size, void* d_ws, size_t ws_size,
                              hipStream_t stream) {
  const float* x    = (const float*)d_in[0];
  const float* W1   = (const float*)d_in[1];
  const float* b1   = (const float*)d_in[2];
  const float* W2   = (const float*)d_in[3];
  const float* b2   = (const float*)d_in[4];
  const float* Wout = (const float*)d_in[5];
  const float* bout = (const float*)d_in[6];
  float* out = (float*)d_out;

  // ---- carve workspace (all 512-aligned) ----
  size_t off = 0;
  char* base = (char*)d_ws;
  auto carve = [&](size_t bytes) -> char* {
    char* r = base + off;
    off += (bytes + 511) & ~(size_t)511;
    return r;
  };
  float* W2T     = (float*)carve((size_t)NH * W2T_STRIDE * 4);
  float* m1state = (float*)carve((size_t)BATCH * 512 * 4);
  float* m2state = (float*)carve((size_t)BATCH * 512 * 4);
  float* cur3T   = (float*)carve((size_t)BATCH * 512 * 2 * 4);   // 512 KB

  const size_t per_t = ((size_t)BATCH * 8 * 8)        // s1seg
                     + ((size_t)BATCH * 8 * 8)        // s2seg
                     + ((size_t)BATCH * CSTRIDE * 4); // cur2seg
  long long avail = (long long)ws_size - (long long)off - 4096;
  int TSEG = (avail > 0) ? (int)(avail / (long long)per_t) : 1;
  if (TSEG > T_STEPS) TSEG = T_STEPS;
  if (TSEG < 1) TSEG = 1;

  ull*   s1seg   = (ull*)carve((size_t)TSEG * BATCH * 8 * 8);
  ull*   s2seg   = (ull*)carve((size_t)TSEG * BATCH * 8 * 8);
  float* cur2seg = (float*)carve((size_t)TSEG * BATCH * CSTRIDE * 4);

  transpose_w2<<<(NH * W2T_STRIDE + 255) / 256, 256, 0, stream>>>(W2, W2T);

  for (int t0 = 0; t0 < T_STEPS; t0 += TSEG) {
    int tc = T_STEPS - t0; if (tc > TSEG) tc = TSEG;
    s1_seg_kernel<<<dim3(BATCH, 2), 256, 0, stream>>>(x, W1, b1, m1state, s1seg, t0, tc);
    cur2_seg_kernel<<<dim3(BATCH, 2), 1024, 0, stream>>>(s1seg, W2T, b2, cur2seg, tc);
    scan2_seg_kernel<<<dim3(BATCH, 4), 64, 0, stream>>>(cur2seg, m2state, s2seg, t0, tc);
    cur3_seg_kernel<<<(tc * BATCH + 3) / 4, 256, 0, stream>>>(s2seg, Wout, cur3T, t0, tc);
  }
  scan3_kernel<<<BATCH, 64, 0, stream>>>(cur3T, bout, out);
}